// Round 2
// 442.839 us; speedup vs baseline: 1.1325x; 1.1325x over previous
//
#include <hip/hip_runtime.h>

#define HID    128
#define GATES  512      // 4*HID
#define EMB    64
#define TSTEPS 1024
#define BATCH  512
#define VOCAB  50257
#define NCLS   28
#define H8STRIDE 160    // h row stride in BYTES (i8 h)
#define TPAD   8        // token row pad (ints)
#define TTAIL  4        // token tail pad: prefetch never needs a clamp

// gate pre-scale folded into proj and w_hh scales: i,f,o -> -log2e; g -> -2log2e
#define S_SIG  (-1.442695041f)
#define S_TANH (-2.885390082f)

typedef __attribute__((ext_vector_type(8))) short short8;   // 8 bf16 = 4 VGPRs
typedef __attribute__((ext_vector_type(4))) float f32x4;
typedef __attribute__((ext_vector_type(4))) unsigned short us4;
typedef __attribute__((ext_vector_type(4))) int int4v;
typedef __attribute__((ext_vector_type(2))) int int2v;

// lgkm-only barrier: LDS visibility without draining global (vmcnt) loads.
#define BAR_LGKM() __asm__ __volatile__("s_waitcnt lgkmcnt(0)\n\ts_barrier" ::: "memory")

static __device__ __forceinline__ float bf2f(unsigned short u){
  union { unsigned int i; float f; } v; v.i = ((unsigned int)u) << 16; return v.f;
}
static __device__ __forceinline__ unsigned short f2bf(float f){
  union { float ff; unsigned int i; } v; v.ff = f;
  unsigned int x = v.i;
  x += 0x7fffu + ((x >> 16) & 1u);   // round-to-nearest-even
  return (unsigned short)(x >> 16);
}

// ---------------------------------------------------------------------------
// Phase 1: proj[v][hcol*4+type] = s_type*(emb[v].w_ih[g] + bias[g]),
// g = type*128 + hcol. 64 vrows/block, 4 waves; operand roles swapped:
//   A (C-rows, m: type=m&3, hcol=hc+(m>>2)) = w_ih rows, B (C-cols) = emb rows.
// Lane's 4 acc regs = the 4 types of one (v,hcol) -> contiguous us4 store,
// no LDS stage, no syncthreads; w_ih conversion amortized over 4 v-tiles.
// Split-bf16 (hi/lo) 3-MFMA product preserved for accuracy.
// ---------------------------------------------------------------------------
__global__ __launch_bounds__(256) void emb_proj_kernel(
    const float* __restrict__ emb,     // [V][64]
    const float* __restrict__ w_ih,    // [512][64]
    const float* __restrict__ b_ih,    // [512]
    const float* __restrict__ b_hh,    // [512]
    unsigned short* __restrict__ proj) // [V][512] interleaved bf16
{
  int wave = threadIdx.x >> 6;         // 0..3
  int lane = threadIdx.x & 63;
  int n = lane & 15;
  int q = lane >> 4;
  long v0 = (long)blockIdx.x * 64;

  // B-operand: emb rows for 4 v-tiles (C-col n -> vrow v0+vt*16+n), split bf16
  short8 bhi[4][2], blo[4][2];
  #pragma unroll
  for (int vt = 0; vt < 4; ++vt){
    long vrow = v0 + vt * 16 + n; if (vrow >= VOCAB) vrow = VOCAB - 1;
    const float* er = emb + vrow * EMB;
    #pragma unroll
    for (int ch = 0; ch < 2; ++ch){
      f32x4 e0 = *(const f32x4*)(er + ch * 32 + q * 8);
      f32x4 e1 = *(const f32x4*)(er + ch * 32 + q * 8 + 4);
      #pragma unroll
      for (int j = 0; j < 4; ++j){
        unsigned short h0 = f2bf(e0[j]);
        bhi[vt][ch][j] = (short)h0;
        blo[vt][ch][j] = (short)f2bf(e0[j] - bf2f(h0));
        unsigned short h1 = f2bf(e1[j]);
        bhi[vt][ch][j + 4] = (short)h1;
        blo[vt][ch][j + 4] = (short)f2bf(e1[j] - bf2f(h1));
      }
    }
  }

  #pragma unroll 1
  for (int i = 0; i < 8; ++i){
    int hc = (wave * 8 + i) * 4;       // hcol group base (4 hcols x 4 types)
    // A-operand: lane n supplies matrix row m=n: gate = (n&3)*128 + hc + (n>>2)
    const float* wr = w_ih + (long)((n & 3) * 128 + hc + (n >> 2)) * EMB;
    short8 ahi[2], alo[2];
    #pragma unroll
    for (int ch = 0; ch < 2; ++ch){
      f32x4 w0 = *(const f32x4*)(wr + ch * 32 + q * 8);
      f32x4 w1 = *(const f32x4*)(wr + ch * 32 + q * 8 + 4);
      #pragma unroll
      for (int j = 0; j < 4; ++j){
        unsigned short h0 = f2bf(w0[j]);
        ahi[ch][j] = (short)h0;
        alo[ch][j] = (short)f2bf(w0[j] - bf2f(h0));
        unsigned short h1 = f2bf(w1[j]);
        ahi[ch][j + 4] = (short)h1;
        alo[ch][j + 4] = (short)f2bf(w1[j] - bf2f(h1));
      }
    }
    // bias for this lane's C rows: acc reg r -> gate r*128 + hc + q
    f32x4 bias;
    #pragma unroll
    for (int r = 0; r < 4; ++r){
      int g = r * 128 + hc + q;
      bias[r] = b_ih[g] + b_hh[g];
    }
    #pragma unroll
    for (int vt = 0; vt < 4; ++vt){
      f32x4 acc = bias;
      #pragma unroll
      for (int ch = 0; ch < 2; ++ch){
        acc = __builtin_amdgcn_mfma_f32_16x16x32_bf16(ahi[ch], bhi[vt][ch], acc, 0, 0, 0);
        acc = __builtin_amdgcn_mfma_f32_16x16x32_bf16(ahi[ch], blo[vt][ch], acc, 0, 0, 0);
        acc = __builtin_amdgcn_mfma_f32_16x16x32_bf16(alo[ch], bhi[vt][ch], acc, 0, 0, 0);
      }
      long v = v0 + vt * 16 + n;
      if (v < VOCAB){
        us4 o;
        #pragma unroll
        for (int r = 0; r < 4; ++r)
          o[r] = f2bf(((r == 2) ? S_TANH : S_SIG) * acc[r]);
        *(us4*)(proj + v * GATES + (hc + q) * 4) = o;   // 8B contiguous store
      }
    }
  }
}

// ---------------------------------------------------------------------------
// Phase 2: LSTM recurrence + final linear. R14 structure + this round's trims:
// (1) magic-constant h quant: fma(hv,127,1.5*2^23) keeps the sum in the
//     [2^23,2^24) binade for NEGATIVE values too (2^23 alone was the R1 bug);
//     low mantissa byte == round(hv*127) mod 256 -> direct signed char store;
// (2) unconditional h8 write from all lanes (dup lanes q/q+2 produce
//     bit-identical h -> same-addr same-value write; kills exec-mask dance);
// (3) tok_lds holds BYTE offsets (tok*GATES*2) -> 32-bit addr add;
// (4) one ds_read_b64 per iteration fetches both substeps' token offsets.
// 256 blocks x 512 threads, R=2, 2 waves/SIMD, i8 16x16x64 MFMA (8/wave),
// per-gate-row max-scaled w_hh, all-lane nonlin via C-row duplicates,
// one lgkm-only barrier per step, depth-2 dwordx2 gx prefetch.
// ---------------------------------------------------------------------------
__global__ __launch_bounds__(512, 2) void lstm_kernel(
    const int* __restrict__ x,           // [512][1024] int32
    const float* __restrict__ w_hh,      // [512][128] f32
    const unsigned short* __restrict__ proj, // [V][512] bf16 interleaved
    const float* __restrict__ w_lin,     // [28][128] f32
    const float* __restrict__ b_lin,     // [28] f32
    float* __restrict__ out)             // [512][28] f32
{
  __shared__ int   tok_lds[2][TSTEPS + TPAD];   // tok*GATES*2 (byte offsets)
  __shared__ signed char h8[2][2][H8STRIDE];    // [buf][row][hcol] i8 h

  int tid  = threadIdx.x;
  int wave = tid >> 6;          // 0..7
  int lane = tid & 63;
  int n = lane & 15;
  int q = lane >> 4;
  int r0 = blockIdx.x * 2;

  // --- preload tokens (pre-multiplied BYTE offsets into proj) -----------
  for (int i = tid; i < TSTEPS + TTAIL; i += 512){
    int src = i < TSTEPS ? i : TSTEPS - 1;
    tok_lds[0][i] = x[(long)r0 * TSTEPS + src] * (GATES * 2);
    tok_lds[1][i] = x[(long)(r0 + 1) * TSTEPS + src] * (GATES * 2);
  }

  // --- quantize w_hh to i8, per-gate-row max scale ----------------------
  // tile t: gate row = t*128 + wave*16 + n; B[k = ch*64 + q*16 + j][n]
  int4v Bw[4][2];
  float scl[4];
  #pragma unroll
  for (int t = 0; t < 4; ++t){
    int row = t * 128 + wave * 16 + n;
    const float* wr = w_hh + (long)row * HID;
    float vals[2][16];
    float m = 0.f;
    #pragma unroll
    for (int ch = 0; ch < 2; ++ch)
      #pragma unroll
      for (int j = 0; j < 16; ++j){
        float v = wr[ch * 64 + q * 16 + j];
        vals[ch][j] = v;
        m = fmaxf(m, fabsf(v));
      }
    m = fmaxf(m, __shfl_xor(m, 16, 64));
    m = fmaxf(m, __shfl_xor(m, 32, 64));
    m = fmaxf(m, 1e-20f);
    float qs = 127.f / m;
    #pragma unroll
    for (int ch = 0; ch < 2; ++ch){
      #pragma unroll
      for (int d = 0; d < 4; ++d){
        int b0 = (int)__builtin_rintf(vals[ch][d * 4 + 0] * qs);
        int b1 = (int)__builtin_rintf(vals[ch][d * 4 + 1] * qs);
        int b2 = (int)__builtin_rintf(vals[ch][d * 4 + 2] * qs);
        int b3 = (int)__builtin_rintf(vals[ch][d * 4 + 3] * qs);
        Bw[t][ch][d] = (b0 & 255) | ((b1 & 255) << 8) | ((b2 & 255) << 16) | (b3 << 24);
      }
    }
    scl[t] = ((t == 2) ? S_TANH : S_SIG) * m * (1.f / 16129.f);  // /127^2
  }

  // zero h buffers (h0 = 0)
  for (int i = tid; i < 2 * 2 * H8STRIDE; i += 512) ((signed char*)h8)[i] = 0;

  float c_state = 0.f;                   // q0/q2: row0 cell; q1/q3: row1 (dups)
  int   arow  = (n >> 2) & 1;            // h row this lane supplies to A
  int   grow  = q & 1;                   // gx row this lane gathers / writes
  int   hcol  = wave * 16 + n;

  const int4v ZERO4 = {0, 0, 0, 0};      // loop-invariant MFMA C operand
  int ghcolB = hcol * 8;                 // byte offset within a proj row

  __syncthreads();                       // tokens + h zeros

  // --- depth-2 gx prefetch ----------------------------------------------
  us4 hxA, hxB;
  hxA = *(const us4*)((const char*)proj + (unsigned)(tok_lds[grow][0] + ghcolB));
  hxB = *(const us4*)((const char*)proj + (unsigned)(tok_lds[grow][1] + ghcolB));

#define SUBSTEP(RB, HX, TOKB)                                                 \
  {                                                                           \
    int4v Af0 = *(const int4v*)(&h8[RB][arow][q * 16]);                       \
    int4v Af1 = *(const int4v*)(&h8[RB][arow][64 + q * 16]);                  \
    /* hoist gx bf16->f32 off the dequant chain */                            \
    float gx0 = bf2f(HX[0]), gx1 = bf2f(HX[1]);                               \
    float gx2 = bf2f(HX[2]), gx3 = bf2f(HX[3]);                               \
    HX = *(const us4*)((const char*)proj + (unsigned)((TOKB) + ghcolB));      \
    /* f-gate tile first: c_state needs sf earliest */                        \
    int4v a1 = __builtin_amdgcn_mfma_i32_16x16x64_i8(Af0, Bw[1][0], ZERO4, 0, 0, 0); \
    a1 = __builtin_amdgcn_mfma_i32_16x16x64_i8(Af1, Bw[1][1], a1, 0, 0, 0);   \
    float g1 = (float)a1[0] * scl[1] + gx1;                                   \
    float ef = __builtin_amdgcn_exp2f(g1);                                    \
    float sf = __builtin_amdgcn_rcpf(1.f + ef);                               \
    int4v a0 = __builtin_amdgcn_mfma_i32_16x16x64_i8(Af0, Bw[0][0], ZERO4, 0, 0, 0); \
    a0 = __builtin_amdgcn_mfma_i32_16x16x64_i8(Af1, Bw[0][1], a0, 0, 0, 0);   \
    float g0 = (float)a0[0] * scl[0] + gx0;                                   \
    float ei = __builtin_amdgcn_exp2f(g0);                                    \
    int4v a2 = __builtin_amdgcn_mfma_i32_16x16x64_i8(Af0, Bw[2][0], ZERO4, 0, 0, 0); \
    a2 = __builtin_amdgcn_mfma_i32_16x16x64_i8(Af1, Bw[2][1], a2, 0, 0, 0);   \
    float g2 = (float)a2[0] * scl[2] + gx2;                                   \
    float eg = __builtin_amdgcn_exp2f(fminf(g2, 126.f));                      \
    int4v a3 = __builtin_amdgcn_mfma_i32_16x16x64_i8(Af0, Bw[3][0], ZERO4, 0, 0, 0); \
    a3 = __builtin_amdgcn_mfma_i32_16x16x64_i8(Af1, Bw[3][1], a3, 0, 0, 0);   \
    float g3 = (float)a3[0] * scl[3] + gx3;                                   \
    float eo = __builtin_amdgcn_exp2f(g3);                                    \
    float r1 = __builtin_amdgcn_rcpf((1.f + ei) * (1.f + eg));                \
    float sitg = (1.f - eg) * r1;             /* si * tg */                   \
    c_state = sf * c_state + sitg;                                            \
    float ec = __builtin_amdgcn_exp2f(fminf(S_TANH * c_state, 126.f));        \
    float r2 = __builtin_amdgcn_rcpf((1.f + eo) * (1.f + ec));                \
    float hv = (1.f - ec) * r2;               /* tanh(c) * so */              \
    /* magic-constant RNE quant: low byte of (hv*127 + 1.5*2^23) */           \
    float qf = __builtin_fmaf(hv, 127.f, 12582912.f);                         \
    h8[(RB) ^ 1][grow][hcol] = (signed char)__float_as_uint(qf);              \
    BAR_LGKM();                                                               \
  }

  for (int step = 0; step < TSTEPS; step += 2){
    int2v tk = *(const int2v*)(&tok_lds[grow][step + 2]);   // both substeps' toks
    SUBSTEP(0, hxA, tk[0])
    SUBSTEP(1, hxB, tk[1])
  }
#undef SUBSTEP

  // --- final linear: out[r0+b][j] = (qh[b]/127) . w_lin[j] + b_lin[j] ---
  // TSTEPS even -> final h is in h8[0]
  if (tid < 2 * NCLS){
    int b = tid / NCLS, j = tid - b * NCLS;
    float s = 0.f;
    const float* wl = w_lin + (long)j * HID;
    #pragma unroll 4
    for (int k = 0; k < HID; ++k)
      s += (float)h8[0][b][k] * wl[k];
    out[(long)(r0 + b) * NCLS + j] = b_lin[j] + s * (1.f / 127.f);
  }
}

// ---------------------------------------------------------------------------
extern "C" void kernel_launch(void* const* d_in, const int* in_sizes, int n_in,
                              void* d_out, int out_size, void* d_ws, size_t ws_size,
                              hipStream_t stream)
{
  const int*   x     = (const int*)d_in[0];
  const float* emb   = (const float*)d_in[1];
  const float* w_ih  = (const float*)d_in[2];
  const float* w_hh  = (const float*)d_in[3];
  const float* b_ih  = (const float*)d_in[4];
  const float* b_hh  = (const float*)d_in[5];
  const float* w_lin = (const float*)d_in[6];
  const float* b_lin = (const float*)d_in[7];
  float*       out   = (float*)d_out;
  unsigned short* proj = (unsigned short*)d_ws;   // [V][512] bf16, ~51.5 MB

  int vblocks = (VOCAB + 63) / 64;   // 786
  emb_proj_kernel<<<dim3(vblocks), dim3(256), 0, stream>>>(
      emb, w_ih, b_ih, b_hh, proj);
  lstm_kernel<<<dim3(BATCH / 2), dim3(512), 0, stream>>>(
      x, w_hh, proj, w_lin, b_lin, out);
}